// Round 13
// baseline (92.189 us; speedup 1.0000x reference)
//
#include <hip/hip_runtime.h>
#include <hip/hip_bf16.h>

typedef __attribute__((ext_vector_type(8))) __bf16 bf16x8;
typedef __attribute__((ext_vector_type(4))) float f32x4;

#define NROWS 16384
#define DIM   2048
#define NH1   512
#define NH2   32
#define MMEM  2048
#define BK    32
#define NT    (DIM / BK)   // 64 K-steps

// workspace byte offsets
#define W1O ((size_t)0)            // W1 bf16:  512*2048*2   = 2097152
#define W2O ((size_t)2097152)      // W2 bf16:  32*512*2     = 32768
#define AMO ((size_t)2129920)      // a_mem:    2048*32*2    = 131072
#define NMO ((size_t)2260992)      // n_mem:    2048*32*2    = 131072
#define HO  ((size_t)2392064)      // h bf16:   16384*512*2  = 16777216

__device__ __forceinline__ f32x4 mfma16(bf16x8 a, bf16x8 b, f32x4 c) {
    return __builtin_amdgcn_mfma_f32_16x16x32_bf16(a, b, c, 0, 0, 0);
}

__device__ __forceinline__ void gload_lds16(const void* g, void* l) {
    __builtin_amdgcn_global_load_lds(
        (const __attribute__((address_space(1))) void*)g,
        (__attribute__((address_space(3))) void*)l, 16, 0, 0);
}

__device__ __forceinline__ bf16x8 cvt8(f32x4 a, f32x4 b) {
    bf16x8 o;
    o[0] = (__bf16)a[0]; o[1] = (__bf16)a[1]; o[2] = (__bf16)a[2]; o[3] = (__bf16)a[3];
    o[4] = (__bf16)b[0]; o[5] = (__bf16)b[1]; o[6] = (__bf16)b[2]; o[7] = (__bf16)b[3];
    return o;
}

// ---------------- merged f32 -> bf16 conversion for W1, W2, am, nm ----------------
struct bf4 { __bf16 a, b, c, d; };

__global__ void cvt_all_kernel(const float* __restrict__ w1f, __bf16* __restrict__ w1b,
                               const float* __restrict__ w2f, __bf16* __restrict__ w2b,
                               const float* __restrict__ amf, __bf16* __restrict__ amb,
                               const float* __restrict__ nmf, __bf16* __restrict__ nmb) {
    const int g = blockIdx.x * blockDim.x + threadIdx.x;
    const int T = gridDim.x * blockDim.x;
    for (int i = g; i < (NH1 * DIM) / 4; i += T) {
        const float4 v = *reinterpret_cast<const float4*>(w1f + i * 4);
        *reinterpret_cast<bf4*>(w1b + i * 4) = { (__bf16)v.x, (__bf16)v.y, (__bf16)v.z, (__bf16)v.w };
    }
    for (int i = g; i < (NH2 * NH1) / 4; i += T) {
        const float4 v = *reinterpret_cast<const float4*>(w2f + i * 4);
        *reinterpret_cast<bf4*>(w2b + i * 4) = { (__bf16)v.x, (__bf16)v.y, (__bf16)v.z, (__bf16)v.w };
    }
    for (int i = g; i < (MMEM * NH2) / 4; i += T) {
        const float4 v = *reinterpret_cast<const float4*>(amf + i * 4);
        *reinterpret_cast<bf4*>(amb + i * 4) = { (__bf16)v.x, (__bf16)v.y, (__bf16)v.z, (__bf16)v.w };
    }
    for (int i = g; i < (MMEM * NH2) / 4; i += T) {
        const float4 v = *reinterpret_cast<const float4*>(nmf + i * 4);
        *reinterpret_cast<bf4*>(nmb + i * 4) = { (__bf16)v.x, (__bf16)v.y, (__bf16)v.z, (__bf16)v.w };
    }
}

// ---------------- GEMM1: h = relu(x @ W1^T + b1) ----------------
// R12 skeleton (tri-buffer, 1 barrier/step, counted vmcnt, stage-after-barrier),
// ONE change: A transported as global->reg(f32)->cvt->bf16 row-packed LDS
// (same 128B-row slot^=(R&7) layout as B). LDS per block-step 72KB -> 48KB.
// 128x128 tile, BK=32, 4 waves (2x2, wave-tile 64x64).
__global__ __launch_bounds__(256, 2) void gemm1_kernel(
    const float*  __restrict__ Xf,  // [NROWS][DIM] f32
    const __bf16* __restrict__ W1,  // [NH1][DIM] bf16
    const float*  __restrict__ b1,  // [NH1]
    __bf16* __restrict__ Hout)      // [NROWS][NH1]
{
    __shared__ __bf16 As[3][64 * 64];    // 8KB per buffer: 64 LDS-rows x 128B,
                                         // LDS-row R holds A-rows {2R,2R+1}
    __shared__ __bf16 Bs[3][128 * BK];   // 8KB per buffer (row-packed, as R12)
    const int tid  = threadIdx.x;
    const int lane = tid & 63;
    const int wave = tid >> 6;
    // XCD swizzle: nwg=512 = 8*64 (bijective)
    const int b = blockIdx.x;
    const int orig = (b & 7) * 64 + (b >> 3);
    const int bn = orig & 3;    // 4 col tiles of 128
    const int bm = orig >> 2;   // 128 row tiles of 128
    const size_t brow = (size_t)bm * 128;
    const int bcol = bn * 128;
    const int wr = wave >> 1, wc = wave & 1;

    f32x4 acc[4][4];
#pragma unroll
    for (int m = 0; m < 4; ++m)
#pragma unroll
        for (int n = 0; n < 4; ++n) acc[m][n] = (f32x4){0.f, 0.f, 0.f, 0.f};

    // ---- A staging (reg, 1-deep): thread t covers LDS-row R=t>>2, half
    // h=(t>>1)&1 (A-row 2R+h), chunks c0=(t&1)*2, c0+1 -> 16 contiguous f32.
    // Stored slots s = (h*4+c) ^ (R&7); bytes R*128 + s*16.
    const int aR  = tid >> 2;
    const int aH  = (tid >> 1) & 1;
    const int aC0 = (tid & 1) * 2;
    const float* aSrc = Xf + (brow + 2 * aR + aH) * (size_t)DIM + aC0 * 8;
    const int aW0 = aR * 128 + (((aH * 4 + aC0)     ^ (aR & 7)) << 4);
    const int aW1 = aR * 128 + (((aH * 4 + aC0 + 1) ^ (aR & 7)) << 4);

    // ---- B staging (DMA, unchanged from R12): 2 gloads/thread, row-packed.
    const int bl  = (tid & 7) ^ ((tid >> 3) & 7);
    const int bh  = bl >> 2;
    const int bc  = bl & 3;
    const __bf16* bSrcBase = W1 + (size_t)(bcol + 2 * (tid >> 3) + bh) * DIM + bc * 8;

#define STAGE_B(T, BI)                                                        \
    {                                                                         \
        const int k0_ = (T) * BK;                                             \
        _Pragma("unroll")                                                     \
        for (int q = 0; q < 2; ++q)                                           \
            gload_lds16(bSrcBase + (size_t)q * 64 * DIM + k0_,                \
                        (char*)Bs[BI] + q * 4096 + tid * 16);                 \
    }

#define LOAD_PA(T)                                                            \
    {                                                                         \
        const float* qs_ = aSrc + (size_t)(T) * BK;                           \
        _Pragma("unroll")                                                     \
        for (int i = 0; i < 4; ++i) pa[i] = *(const f32x4*)(qs_ + i * 4);     \
    }

#define WRITE_A(BI)                                                           \
    {                                                                         \
        *(bf16x8*)((char*)As[BI] + aW0) = cvt8(pa[0], pa[1]);                 \
        *(bf16x8*)((char*)As[BI] + aW1) = cvt8(pa[2], pa[3]);                 \
    }

    // ---- fragment read geometry: both A and B use row-packed 128B rows.
    // tile-row r = base + n*16 + l15 -> LDS-row R = base/2 + n*8 + (l15>>1),
    // slot = ((l15&1)*4 + kc) ^ (l15>>1). 2 lanes/bank-group = free.
    const int l15 = lane & 15;
    const int kc  = lane >> 4;
    const int slotB = ((((l15 & 1) * 4 + kc) ^ (l15 >> 1)) << 4);
    const int aByteBase = (wr * 32 + (l15 >> 1)) * 128 + slotB;
    const int bByteBase = (wc * 32 + (l15 >> 1)) * 128 + slotB;

#define COMPUTE(BI)                                                           \
    {                                                                         \
        const char* Ac = (const char*)As[BI];                                 \
        const char* Bc = (const char*)Bs[BI];                                 \
        bf16x8 av[4], bv[4];                                                  \
        _Pragma("unroll")                                                     \
        for (int m = 0; m < 4; ++m)                                           \
            av[m] = *(const bf16x8*)(Ac + aByteBase + m * 1024);              \
        _Pragma("unroll")                                                     \
        for (int n = 0; n < 4; ++n)                                           \
            bv[n] = *(const bf16x8*)(Bc + bByteBase + n * 1024);              \
        __builtin_amdgcn_s_setprio(1);                                        \
        _Pragma("unroll")                                                     \
        for (int m = 0; m < 4; ++m)                                           \
            _Pragma("unroll")                                                 \
            for (int n = 0; n < 4; ++n)                                       \
                acc[m][n] = mfma16(av[m], bv[n], acc[m][n]);                  \
        __builtin_amdgcn_s_setprio(0);                                        \
    }

    f32x4 pa[4];

    // ===== prologue: stage 0 fully; pa = A(1); B(1) DMA in flight =====
    STAGE_B(0, 0);
    LOAD_PA(0);
    WRITE_A(0);          // implicit wait drains pa(0) (+B(0), older) - one-time
    STAGE_B(1, 1);
    LOAD_PA(1);

    // ===== main loop: t = 0 .. NT-3 =====
    // top wait: in-flight = B(t+1)x2 + pa(t+1)x4 = 6 -> vmcnt(6) safety;
    // lgkmcnt(0) makes A(t) ds_writes visible; barrier.
    // Then: B-DMA(t+2) | WRITE_A(t+1) [implicit vmcnt(2): drains pa(t+1)+B(t+1),
    // both 1 iter old] | LOAD_PA(t+2) | COMPUTE(t).
    for (int t = 0; t < NT - 2; ++t) {
        asm volatile("s_waitcnt vmcnt(6) lgkmcnt(0)" ::: "memory");
        __builtin_amdgcn_s_barrier();
        __builtin_amdgcn_sched_barrier(0);
        STAGE_B(t + 2, (t + 2) % 3);
        __builtin_amdgcn_sched_barrier(0);
        WRITE_A((t + 1) % 3);
        __builtin_amdgcn_sched_barrier(0);
        LOAD_PA(t + 2);
        __builtin_amdgcn_sched_barrier(0);
        COMPUTE(t % 3);
    }
    // t = NT-2: pa holds A(NT-1); B(NT-1) in flight
    {
        asm volatile("s_waitcnt vmcnt(6) lgkmcnt(0)" ::: "memory");
        __builtin_amdgcn_s_barrier();
        __builtin_amdgcn_sched_barrier(0);
        WRITE_A((NT - 1) % 3);   // implicit wait drains pa(NT-1)+B(NT-1)
        __builtin_amdgcn_sched_barrier(0);
        COMPUTE((NT - 2) % 3);
    }
    // t = NT-1
    {
        asm volatile("s_waitcnt vmcnt(0) lgkmcnt(0)" ::: "memory");
        __builtin_amdgcn_s_barrier();
        __builtin_amdgcn_sched_barrier(0);
        COMPUTE((NT - 1) % 3);
    }
#undef STAGE_B
#undef LOAD_PA
#undef WRITE_A
#undef COMPUTE

    // epilogue: bias + relu + bf16 store. D layout: col=lane&15, row=(lane>>4)*4+reg
#pragma unroll
    for (int n = 0; n < 4; ++n) {
        const int gcol = bcol + wc * 64 + n * 16 + l15;
        const float bias = b1[gcol];
#pragma unroll
        for (int m = 0; m < 4; ++m) {
            const size_t grow0 = brow + wr * 64 + m * 16 + kc * 4;
#pragma unroll
            for (int r = 0; r < 4; ++r) {
                float v = acc[m][n][r] + bias;
                v = v > 0.f ? v : 0.f;
                Hout[(grow0 + r) * NH1 + gcol] = (__bf16)v;
            }
        }
    }
}

// ---------------- Tail: feat = h@W2^T + b2; scores; sigmoid ----------------
__global__ __launch_bounds__(512) void tail_kernel(
    const __bf16* __restrict__ Hin,  // [NROWS][NH1]
    const __bf16* __restrict__ W2b,  // [NH2][NH1]
    const float*  __restrict__ b2,   // [NH2]
    const __bf16* __restrict__ Am,   // [MMEM][NH2]
    const __bf16* __restrict__ Nm,   // [MMEM][NH2]
    float* __restrict__ out)         // [NROWS]
{
    __shared__ __bf16 featLds[64 * 32];
    __shared__ float aMaxLds[2][64];
    __shared__ float nMaxLds[2][64];
    const int tid  = threadIdx.x;
    const int lane = tid & 63;
    const int wave = tid >> 6;          // 0..7
    const int rowBase = blockIdx.x * 64;
    const int l15 = lane & 15;
    const int kc  = lane >> 4;
    const int rgrp  = (wave & 3) * 16;
    const int jHalf = wave >> 2;

    if (wave < 4) {
        f32x4 acc0 = {0.f,0.f,0.f,0.f}, acc1 = {0.f,0.f,0.f,0.f};
        const size_t hrow = (size_t)(rowBase + rgrp + l15) * NH1;
#pragma unroll
        for (int kk = 0; kk < 16; ++kk) {
            bf16x8 a  = *(const bf16x8*)(Hin + hrow + kk * 32 + kc * 8);
            bf16x8 w0 = *(const bf16x8*)(W2b + (size_t)l15 * NH1 + kk * 32 + kc * 8);
            bf16x8 w1 = *(const bf16x8*)(W2b + (size_t)(16 + l15) * NH1 + kk * 32 + kc * 8);
            acc0 = mfma16(a, w0, acc0);
            acc1 = mfma16(a, w1, acc1);
        }
        const float bias0 = b2[l15], bias1 = b2[16 + l15];
#pragma unroll
        for (int r = 0; r < 4; ++r) {
            const int lr = rgrp + kc * 4 + r;
            featLds[lr * 32 + l15]      = (__bf16)(acc0[r] + bias0);
            featLds[lr * 32 + 16 + l15] = (__bf16)(acc1[r] + bias1);
        }
    }
    __syncthreads();

    const bf16x8 af = *(const bf16x8*)&featLds[(rgrp + l15) * 32 + kc * 8];

    float rmaxA[4], rmaxN[4];
#pragma unroll
    for (int r = 0; r < 4; ++r) { rmaxA[r] = -1e30f; rmaxN[r] = -1e30f; }
    const f32x4 zero = {0.f,0.f,0.f,0.f};
    const int jBase = jHalf * (MMEM / 2);
#pragma unroll 2
    for (int jt = 0; jt < (MMEM / 2) / 16; jt += 4) {
        bf16x8 ba[4], bb[4];
#pragma unroll
        for (int u = 0; u < 4; ++u) {
            const size_t off = (size_t)(jBase + (jt + u) * 16 + l15) * NH2 + kc * 8;
            ba[u] = *(const bf16x8*)(Am + off);
            bb[u] = *(const bf16x8*)(Nm + off);
        }
#pragma unroll
        for (int u = 0; u < 4; ++u) {
            f32x4 sa = mfma16(af, ba[u], zero);
            f32x4 sn = mfma16(af, bb[u], zero);
#pragma unroll
            for (int r = 0; r < 4; ++r) {
                rmaxA[r] = fmaxf(rmaxA[r], sa[r]);
                rmaxN[r] = fmaxf(rmaxN[r], sn[r]);
            }
        }
    }
#pragma unroll
    for (int off = 1; off < 16; off <<= 1) {
#pragma unroll
        for (int r = 0; r < 4; ++r) {
            rmaxA[r] = fmaxf(rmaxA[r], __shfl_xor(rmaxA[r], off, 64));
            rmaxN[r] = fmaxf(rmaxN[r], __shfl_xor(rmaxN[r], off, 64));
        }
    }
    if (l15 == 0) {
#pragma unroll
        for (int r = 0; r < 4; ++r) {
            const int row = rgrp + kc * 4 + r;
            aMaxLds[jHalf][row] = rmaxA[r];
            nMaxLds[jHalf][row] = rmaxN[r];
        }
    }
    __syncthreads();
    if (tid < 64) {
        const float ma = fmaxf(aMaxLds[0][tid], aMaxLds[1][tid]);
        const float mn = fmaxf(nMaxLds[0][tid], nMaxLds[1][tid]);
        const float d = (ma - mn) * (1.0f / 32.0f);
        out[rowBase + tid] = 1.0f / (1.0f + __expf(-d));
    }
}

extern "C" void kernel_launch(void* const* d_in, const int* in_sizes, int n_in,
                              void* d_out, int out_size, void* d_ws, size_t ws_size,
                              hipStream_t stream) {
    (void)in_sizes; (void)n_in; (void)out_size; (void)ws_size;
    const float* x  = (const float*)d_in[0];
    const float* W1 = (const float*)d_in[1];
    const float* b1 = (const float*)d_in[2];
    const float* W2 = (const float*)d_in[3];
    const float* b2 = (const float*)d_in[4];
    const float* am = (const float*)d_in[5];
    const float* nm = (const float*)d_in[6];
    float* out = (float*)d_out;
    char* ws = (char*)d_ws;
    __bf16* w1b = (__bf16*)(ws + W1O);
    __bf16* w2b = (__bf16*)(ws + W2O);
    __bf16* amb = (__bf16*)(ws + AMO);
    __bf16* nmb = (__bf16*)(ws + NMO);
    __bf16* hb  = (__bf16*)(ws + HO);

    cvt_all_kernel<<<dim3(512), dim3(256), 0, stream>>>(W1, w1b, W2, w2b, am, amb, nm, nmb);
    gemm1_kernel<<<dim3((NROWS / 128) * (NH1 / 128)), dim3(256), 0, stream>>>(x, w1b, b1, hb);
    tail_kernel<<<dim3(NROWS / 64), dim3(512), 0, stream>>>(hb, w2b, b2, amb, nmb, out);
}